// Round 1
// baseline (116.505 us; speedup 1.0000x reference)
//
#include <hip/hip_runtime.h>

#define NSTATE 128
#define NM1    127
#define UDIM   4

__global__ __launch_bounds__(256) void llm_markov_kernel(
    const int*   __restrict__ x_curr,
    const float* __restrict__ u_curr,
    const float* __restrict__ logP0,
    const float* __restrict__ W,
    float*       __restrict__ out,
    int T)
{
    const int lane          = threadIdx.x & 63;
    const int wave_in_block = threadIdx.x >> 6;
    const int waves_per_blk = blockDim.x >> 6;
    const int wave_id       = blockIdx.x * waves_per_blk + wave_in_block;
    const int nwaves        = gridDim.x * waves_per_blk;

    const int j0 = 2 * lane;
    const int j1 = 2 * lane + 1;

    for (int t = wave_id; t < T; t += nwaves) {
        // wave-uniform state index -> SGPR
        int s = x_curr[t];
        s = __builtin_amdgcn_readfirstlane(s);

        // broadcast u row (16B aligned)
        const float4 u = *reinterpret_cast<const float4*>(u_curr + (size_t)t * UDIM);

        // stimulus for this lane's two columns; self column -> 0 (pad slot)
        float stim0 = 0.0f, stim1 = 0.0f;
        if (j0 != s) {
            const int k = j0 - (j0 > s);
            const float4 w = *reinterpret_cast<const float4*>(W + ((size_t)s * NM1 + k) * UDIM);
            stim0 = u.x * w.x + u.y * w.y + u.z * w.z + u.w * w.w;
        }
        if (j1 != s) {
            const int k = j1 - (j1 > s);
            const float4 w = *reinterpret_cast<const float4*>(W + ((size_t)s * NM1 + k) * UDIM);
            stim1 = u.x * w.x + u.y * w.y + u.z * w.z + u.w * w.w;
        }

        const float2 lp = *reinterpret_cast<const float2*>(logP0 + (size_t)s * NSTATE + j0);
        float v0 = lp.x + stim0;
        float v1 = lp.y + stim1;

        // wave-wide max (butterfly over 64 lanes)
        float m = fmaxf(v0, v1);
        #pragma unroll
        for (int off = 32; off >= 1; off >>= 1)
            m = fmaxf(m, __shfl_xor(m, off, 64));

        // wave-wide sum of exp
        float e = __expf(v0 - m) + __expf(v1 - m);
        #pragma unroll
        for (int off = 32; off >= 1; off >>= 1)
            e += __shfl_xor(e, off, 64);

        const float lse = m + __logf(e);

        float2 o;
        o.x = v0 - lse;
        o.y = v1 - lse;
        *reinterpret_cast<float2*>(out + (size_t)t * NSTATE + j0) = o;
    }
}

extern "C" void kernel_launch(void* const* d_in, const int* in_sizes, int n_in,
                              void* d_out, int out_size, void* d_ws, size_t ws_size,
                              hipStream_t stream) {
    const int*   x_curr = (const int*)  d_in[0];
    const float* u_curr = (const float*)d_in[1];
    const float* logP0  = (const float*)d_in[2];
    const float* W      = (const float*)d_in[3];
    float*       out    = (float*)d_out;

    const int T = in_sizes[0];

    // 2048 blocks x 256 threads = 8192 waves = full occupancy on 256 CUs,
    // grid-stride ~61 rows per wave.
    dim3 grid(2048), block(256);
    hipLaunchKernelGGL(llm_markov_kernel, grid, block, 0, stream,
                       x_curr, u_curr, logP0, W, out, T);
}